// Round 2
// baseline (590.680 us; speedup 1.0000x reference)
//
#include <hip/hip_runtime.h>

// 2-layer tanh RNN, B=2048, S=512, I=1, H=64, O=1.
// One wave (64 lanes) per batch element; lane i owns hidden unit i and keeps
// the full weight rows W_hh0[i][:], W_ih1[i][:], W_hh1[i][:] in VGPRs.
// Hidden state broadcast via wave-private LDS buffer (uniform-address float4
// reads = LDS broadcast, conflict-free). No inter-workgroup communication.

#define HID 64
#define SEQ 512

__device__ __forceinline__ float tanh_fast(float x) {
    // tanh(x) = 1 - 2/(exp(2x)+1);  exp(2x) = exp2(x * 2*log2(e))
    float e = __builtin_amdgcn_exp2f(x * 2.8853900817779268f);  // v_exp_f32
    return 1.0f - 2.0f * __builtin_amdgcn_rcpf(e + 1.0f);       // v_rcp_f32
}

#define FMA4(acc, warr, base, vec)            \
    acc = fmaf(warr[(base)+0], (vec).x, acc); \
    acc = fmaf(warr[(base)+1], (vec).y, acc); \
    acc = fmaf(warr[(base)+2], (vec).z, acc); \
    acc = fmaf(warr[(base)+3], (vec).w, acc);

__global__ __launch_bounds__(64, 2)
void rnn2_fused_kernel(const float* __restrict__ x,      // [B][SEQ] (I=1)
                       const float* __restrict__ W_ih0,  // [HID][1]
                       const float* __restrict__ W_hh0,  // [HID][HID]
                       const float* __restrict__ b_ih0,  // [HID]
                       const float* __restrict__ b_hh0,  // [HID]
                       const float* __restrict__ W_ih1,  // [HID][HID]
                       const float* __restrict__ W_hh1,  // [HID][HID]
                       const float* __restrict__ b_ih1,  // [HID]
                       const float* __restrict__ b_hh1,  // [HID]
                       const float* __restrict__ fc_W,   // [1][HID]
                       const float* __restrict__ fc_b,   // [1]
                       float* __restrict__ out)          // [B]
{
    __shared__ __align__(16) float x_lds[SEQ];
    __shared__ __align__(16) float h1_lds[HID];
    __shared__ __align__(16) float h2_lds[HID];

    const int lane = threadIdx.x;   // 0..63 = output hidden unit
    const int b    = blockIdx.x;    // batch element

    // --- Preload weight rows into registers (192 VGPRs) ---
    float w0[HID], wi1[HID], w1[HID];
#pragma unroll
    for (int j = 0; j < HID; j += 4) {
        *reinterpret_cast<float4*>(&w0[j])  = *reinterpret_cast<const float4*>(&W_hh0[lane * HID + j]);
        *reinterpret_cast<float4*>(&wi1[j]) = *reinterpret_cast<const float4*>(&W_ih1[lane * HID + j]);
        *reinterpret_cast<float4*>(&w1[j])  = *reinterpret_cast<const float4*>(&W_hh1[lane * HID + j]);
    }
    const float win0  = W_ih0[lane];
    const float bias0 = b_ih0[lane] + b_hh0[lane];
    const float bias1 = b_ih1[lane] + b_hh1[lane];

    // --- Stage this batch's x sequence into LDS (coalesced) ---
#pragma unroll
    for (int t = 0; t < SEQ / HID; ++t)
        x_lds[t * HID + lane] = x[(size_t)b * SEQ + t * HID + lane];

    h1_lds[lane] = 0.0f;
    h2_lds[lane] = 0.0f;
    __syncthreads();

    float h2n = 0.0f;

#pragma unroll 1
    for (int s = 0; s < SEQ; ++s) {
        // ---- mv1 (W_hh0 . h1_prev) and mv3 (W_hh1 . h2_prev), merged ----
        float a1a = 0.f, a1b = 0.f, a3a = 0.f, a3b = 0.f;
#pragma unroll
        for (int j = 0; j < HID; j += 8) {
            const float4 p = *reinterpret_cast<const float4*>(&h1_lds[j]);
            const float4 q = *reinterpret_cast<const float4*>(&h1_lds[j + 4]);
            const float4 r = *reinterpret_cast<const float4*>(&h2_lds[j]);
            const float4 t = *reinterpret_cast<const float4*>(&h2_lds[j + 4]);
            FMA4(a1a, w0, j,     p);
            FMA4(a1b, w0, j + 4, q);
            FMA4(a3a, w1, j,     r);
            FMA4(a3b, w1, j + 4, t);
        }

        const float xs  = x_lds[s];
        const float h1n = tanh_fast(a1a + a1b + fmaf(xs, win0, bias0));
        h1_lds[lane] = h1n;
        __syncthreads();

        // ---- mv2 (W_ih1 . h1_new) ----
        float a2a = 0.f, a2b = 0.f;
#pragma unroll
        for (int j = 0; j < HID; j += 8) {
            const float4 p = *reinterpret_cast<const float4*>(&h1_lds[j]);
            const float4 q = *reinterpret_cast<const float4*>(&h1_lds[j + 4]);
            FMA4(a2a, wi1, j,     p);
            FMA4(a2b, wi1, j + 4, q);
        }

        h2n = tanh_fast(a2a + a2b + a3a + a3b + bias1);
        h2_lds[lane] = h2n;
        __syncthreads();
    }

    // ---- Final FC: out[b] = sum_i h2[i] * fc_W[i] + fc_b ----
    float v = h2n * fc_W[lane];
#pragma unroll
    for (int off = 32; off > 0; off >>= 1)
        v += __shfl_xor(v, off, 64);
    if (lane == 0)
        out[b] = v + fc_b[0];
}

extern "C" void kernel_launch(void* const* d_in, const int* in_sizes, int n_in,
                              void* d_out, int out_size, void* d_ws, size_t ws_size,
                              hipStream_t stream) {
    const float* x     = (const float*)d_in[0];
    const float* W_ih0 = (const float*)d_in[1];
    const float* W_hh0 = (const float*)d_in[2];
    const float* b_ih0 = (const float*)d_in[3];
    const float* b_hh0 = (const float*)d_in[4];
    const float* W_ih1 = (const float*)d_in[5];
    const float* W_hh1 = (const float*)d_in[6];
    const float* b_ih1 = (const float*)d_in[7];
    const float* b_hh1 = (const float*)d_in[8];
    const float* fc_W  = (const float*)d_in[9];
    const float* fc_b  = (const float*)d_in[10];

    rnn2_fused_kernel<<<dim3(2048), dim3(64), 0, stream>>>(
        x, W_ih0, W_hh0, b_ih0, b_hh0, W_ih1, W_hh1, b_ih1, b_hh1,
        fc_W, fc_b, (float*)d_out);
}

// Round 3
// 490.750 us; speedup vs baseline: 1.2036x; 1.2036x over previous
//
#include <hip/hip_runtime.h>

// 2-layer tanh RNN, B=2048, S=512, I=1, H=64, O=1.
// One wave per batch element; lane i owns hidden unit i; weight rows
// W_hh0[i][:], W_ih1[i][:], W_hh1[i][:] live in VGPRs (192 regs) —
// amdgpu_waves_per_eu(2,2) lets the allocator use up to 256 VGPRs.
// The two layers are software-pipelined: iteration k computes h1[k] and
// h2[k-1], so both W_hh0 and W_ih1 matvecs share one LDS broadcast of
// h1[k-1] (32 ds_read_b128/step instead of 48) and no intra-step barrier
// is needed. Single-wave blocks -> no __syncthreads at all (DS ops are
// in-order within a wave).

#define HID 64
#define SEQ 512

__device__ __forceinline__ float tanh_fast(float x) {
    // tanh(x) = 1 - 2/(exp(2x)+1);  exp(2x) = exp2(x * 2*log2(e))
    float e = __builtin_amdgcn_exp2f(x * 2.8853900817779268f);  // v_exp_f32
    return 1.0f - 2.0f * __builtin_amdgcn_rcpf(e + 1.0f);       // v_rcp_f32
}

#define FMA4(acc, warr, base, vec)            \
    acc = fmaf(warr[(base)+0], (vec).x, acc); \
    acc = fmaf(warr[(base)+1], (vec).y, acc); \
    acc = fmaf(warr[(base)+2], (vec).z, acc); \
    acc = fmaf(warr[(base)+3], (vec).w, acc);

__attribute__((amdgpu_waves_per_eu(2, 2)))
__global__ void __launch_bounds__(64)
rnn2_fused_kernel(const float* __restrict__ x,      // [B][SEQ] (I=1)
                  const float* __restrict__ W_ih0,  // [HID][1]
                  const float* __restrict__ W_hh0,  // [HID][HID]
                  const float* __restrict__ b_ih0,  // [HID]
                  const float* __restrict__ b_hh0,  // [HID]
                  const float* __restrict__ W_ih1,  // [HID][HID]
                  const float* __restrict__ W_hh1,  // [HID][HID]
                  const float* __restrict__ b_ih1,  // [HID]
                  const float* __restrict__ b_hh1,  // [HID]
                  const float* __restrict__ fc_W,   // [1][HID]
                  const float* __restrict__ fc_b,   // [1]
                  float* __restrict__ out)          // [B]
{
    __shared__ __align__(16) float x_lds[SEQ];
    __shared__ __align__(16) float h1_lds[HID];
    __shared__ __align__(16) float h2_lds[HID];

    const int lane = threadIdx.x;   // 0..63 = hidden unit
    const int b    = blockIdx.x;    // batch element

    // --- Preload weight rows into registers (scalar stores -> clean SROA) ---
    float w0[HID], wi1[HID], w1[HID];
#pragma unroll
    for (int j = 0; j < HID; j += 4) {
        const float4 a = *reinterpret_cast<const float4*>(&W_hh0[lane * HID + j]);
        const float4 c = *reinterpret_cast<const float4*>(&W_ih1[lane * HID + j]);
        const float4 d = *reinterpret_cast<const float4*>(&W_hh1[lane * HID + j]);
        w0[j]  = a.x; w0[j+1]  = a.y; w0[j+2]  = a.z; w0[j+3]  = a.w;
        wi1[j] = c.x; wi1[j+1] = c.y; wi1[j+2] = c.z; wi1[j+3] = c.w;
        w1[j]  = d.x; w1[j+1]  = d.y; w1[j+2]  = d.z; w1[j+3]  = d.w;
    }
    const float win0  = W_ih0[lane];
    const float bias0 = b_ih0[lane] + b_hh0[lane];
    const float bias1 = b_ih1[lane] + b_hh1[lane];

    // --- Stage this batch's x sequence into LDS (coalesced) ---
#pragma unroll
    for (int t = 0; t < SEQ / HID; ++t)
        x_lds[t * HID + lane] = x[(size_t)b * SEQ + t * HID + lane];

    h2_lds[lane] = 0.0f;                     // h2[-1] = 0 (read at k=1)

    // --- Peel k=0: h1[0] = tanh(x[0]*win0 + bias0), h1[-1] = 0 ---
    {
        const float h1n = tanh_fast(fmaf(x_lds[0], win0, bias0));
        h1_lds[lane] = h1n;
    }

    // --- Main loop: iteration k computes h1[k] and h2[k-1]. ---
    // Entering iter k: h1_lds = h1[k-1], h2_lds = h2[k-2].
#pragma unroll 1
    for (int k = 1; k < SEQ; ++k) {
        float a1a = 0.f, a1b = 0.f;   // W_hh0 . h1[k-1]
        float a2a = 0.f, a2b = 0.f;   // W_ih1 . h1[k-1]
        float a3a = 0.f, a3b = 0.f;   // W_hh1 . h2[k-2]
#pragma unroll
        for (int j = 0; j < HID; j += 8) {
            const float4 p = *reinterpret_cast<const float4*>(&h1_lds[j]);
            const float4 q = *reinterpret_cast<const float4*>(&h1_lds[j + 4]);
            const float4 r = *reinterpret_cast<const float4*>(&h2_lds[j]);
            const float4 t = *reinterpret_cast<const float4*>(&h2_lds[j + 4]);
            FMA4(a1a, w0,  j,     p);
            FMA4(a1b, w0,  j + 4, q);
            FMA4(a2a, wi1, j,     p);
            FMA4(a2b, wi1, j + 4, q);
            FMA4(a3a, w1,  j,     r);
            FMA4(a3b, w1,  j + 4, t);
        }
        const float h1n = tanh_fast(a1a + a1b + fmaf(x_lds[k], win0, bias0));
        const float h2n = tanh_fast(a2a + a2b + a3a + a3b + bias1);
        h1_lds[lane] = h1n;   // h1[k]
        h2_lds[lane] = h2n;   // h2[k-1]
    }

    // --- Epilogue: h2[SEQ-1] from h1[SEQ-1] and h2[SEQ-2] ---
    float a2a = 0.f, a2b = 0.f, a3a = 0.f, a3b = 0.f;
#pragma unroll
    for (int j = 0; j < HID; j += 8) {
        const float4 p = *reinterpret_cast<const float4*>(&h1_lds[j]);
        const float4 q = *reinterpret_cast<const float4*>(&h1_lds[j + 4]);
        const float4 r = *reinterpret_cast<const float4*>(&h2_lds[j]);
        const float4 t = *reinterpret_cast<const float4*>(&h2_lds[j + 4]);
        FMA4(a2a, wi1, j,     p);
        FMA4(a2b, wi1, j + 4, q);
        FMA4(a3a, w1,  j,     r);
        FMA4(a3b, w1,  j + 4, t);
    }
    const float h2last = tanh_fast(a2a + a2b + a3a + a3b + bias1);

    // --- Final FC: out[b] = sum_i h2[i] * fc_W[i] + fc_b ---
    float v = h2last * fc_W[lane];
#pragma unroll
    for (int off = 32; off > 0; off >>= 1)
        v += __shfl_xor(v, off, 64);
    if (lane == 0)
        out[b] = v + fc_b[0];
}

extern "C" void kernel_launch(void* const* d_in, const int* in_sizes, int n_in,
                              void* d_out, int out_size, void* d_ws, size_t ws_size,
                              hipStream_t stream) {
    const float* x     = (const float*)d_in[0];
    const float* W_ih0 = (const float*)d_in[1];
    const float* W_hh0 = (const float*)d_in[2];
    const float* b_ih0 = (const float*)d_in[3];
    const float* b_hh0 = (const float*)d_in[4];
    const float* W_ih1 = (const float*)d_in[5];
    const float* W_hh1 = (const float*)d_in[6];
    const float* b_ih1 = (const float*)d_in[7];
    const float* b_hh1 = (const float*)d_in[8];
    const float* fc_W  = (const float*)d_in[9];
    const float* fc_b  = (const float*)d_in[10];

    rnn2_fused_kernel<<<dim3(2048), dim3(64), 0, stream>>>(
        x, W_ih0, W_hh0, b_ih0, b_hh0, W_ih1, W_hh1, b_ih1, b_hh1,
        fc_W, fc_b, (float*)d_out);
}